// Round 4
// baseline (227.247 us; speedup 1.0000x reference)
//
#include <hip/hip_runtime.h>
#include <math.h>

#define NPV 3072
#define LDP 3073
#define EPSF 1e-8f

// Branchless insert of v into sorted-descending triple (a >= b >= c).
#define INS3(v, a, b, c) do { \
    float _m1 = fminf((a), (v)); (a) = fmaxf((a), (v)); \
    float _m2 = fminf((b), _m1); (b) = fmaxf((b), _m1); \
    (c) = fmaxf((c), _m2); } while (0)

#define MRG3(x, y, z, a, b, c) do { \
    INS3((x), a, b, c); INS3((y), a, b, c); INS3((z), a, b, c); } while (0)

// One wave per row (4 rows/block), branchless values-only top-3.
__global__ __launch_bounds__(256) void k_row_top3(const float* __restrict__ P,
        float* __restrict__ tr, int* __restrict__ rowcnt)
{
    int lane = threadIdx.x & 63;
    int i = blockIdx.x * 4 + (threadIdx.x >> 6);
    const float* row = P + (size_t)i * LDP;
    float a0 = -1e30f, b0 = -1e30f, c0 = -1e30f;
    float a1 = -1e30f, b1 = -1e30f, c1 = -1e30f;
    float a2 = -1e30f, b2 = -1e30f, c2 = -1e30f;
    float a3 = -1e30f, b3 = -1e30f, c3 = -1e30f;
    #pragma unroll
    for (int r = 0; r < 48; r += 4) {
        float v0 = row[(r + 0) * 64 + lane];
        float v1 = row[(r + 1) * 64 + lane];
        float v2 = row[(r + 2) * 64 + lane];
        float v3 = row[(r + 3) * 64 + lane];
        INS3(v0, a0, b0, c0);
        INS3(v1, a1, b1, c1);
        INS3(v2, a2, b2, c2);
        INS3(v3, a3, b3, c3);
    }
    MRG3(a1, b1, c1, a0, b0, c0);
    MRG3(a2, b2, c2, a0, b0, c0);
    MRG3(a3, b3, c3, a0, b0, c0);
    #pragma unroll
    for (int off = 1; off < 64; off <<= 1) {
        float xa = __shfl_xor(a0, off);
        float xb = __shfl_xor(b0, off);
        float xc = __shfl_xor(c0, off);
        MRG3(xa, xb, xc, a0, b0, c0);
    }
    if (lane == 0) { tr[i] = c0; rowcnt[i] = 0; }
}

#define CAND(v, i) do { \
    if ((v) >= tr[i] && (v) > 0.01f) { \
        int _s = atomicAdd(&rowcnt[i], 1); \
        if (_s < 8) { rowj[(size_t)(i) * 8 + _s] = j; roww[(size_t)(i) * 8 + _s] = (v); } \
    } } while (0)

__global__ __launch_bounds__(256) void k_col_pass(const float* __restrict__ P,
        const float* __restrict__ tr, float* __restrict__ part, int segrows,
        int* __restrict__ rowcnt, int* __restrict__ rowj, float* __restrict__ roww)
{
    int j = blockIdx.x * 256 + threadIdx.x;
    int i0 = blockIdx.y * segrows;
    float a0 = -1e30f, b0 = -1e30f, c0 = -1e30f;
    float a1 = -1e30f, b1 = -1e30f, c1 = -1e30f;
    float a2 = -1e30f, b2 = -1e30f, c2 = -1e30f;
    float a3 = -1e30f, b3 = -1e30f, c3 = -1e30f;
    float a4 = -1e30f, b4 = -1e30f, c4 = -1e30f;
    float a5 = -1e30f, b5 = -1e30f, c5 = -1e30f;
    float a6 = -1e30f, b6 = -1e30f, c6 = -1e30f;
    float a7 = -1e30f, b7 = -1e30f, c7 = -1e30f;
    for (int r = 0; r < segrows; r += 8) {
        int i = i0 + r;
        const float* col = P + (size_t)i * LDP + j;
        float v0 = col[0 * LDP];
        float v1 = col[1 * LDP];
        float v2 = col[2 * LDP];
        float v3 = col[3 * LDP];
        float v4 = col[4 * LDP];
        float v5 = col[5 * LDP];
        float v6 = col[6 * LDP];
        float v7 = col[7 * LDP];
        INS3(v0, a0, b0, c0);
        INS3(v1, a1, b1, c1);
        INS3(v2, a2, b2, c2);
        INS3(v3, a3, b3, c3);
        INS3(v4, a4, b4, c4);
        INS3(v5, a5, b5, c5);
        INS3(v6, a6, b6, c6);
        INS3(v7, a7, b7, c7);
        CAND(v0, i + 0);
        CAND(v1, i + 1);
        CAND(v2, i + 2);
        CAND(v3, i + 3);
        CAND(v4, i + 4);
        CAND(v5, i + 5);
        CAND(v6, i + 6);
        CAND(v7, i + 7);
    }
    MRG3(a1, b1, c1, a0, b0, c0);
    MRG3(a2, b2, c2, a0, b0, c0);
    MRG3(a3, b3, c3, a0, b0, c0);
    MRG3(a4, b4, c4, a0, b0, c0);
    MRG3(a5, b5, c5, a0, b0, c0);
    MRG3(a6, b6, c6, a0, b0, c0);
    MRG3(a7, b7, c7, a0, b0, c0);
    size_t o = ((size_t)blockIdx.y * NPV + j) * 3;
    part[o] = a0; part[o + 1] = b0; part[o + 2] = c0;
}

__global__ __launch_bounds__(64) void k_col_merge(const float* __restrict__ part,
        float* __restrict__ tc, int nseg)
{
    int j = blockIdx.x * 64 + threadIdx.x;
    float a = -1e30f, b = -1e30f, c = -1e30f;
    for (int s = 0; s < nseg; ++s) {
        size_t o = ((size_t)s * NPV + j) * 3;
        float x = part[o], y = part[o + 1], z = part[o + 2];
        MRG3(x, y, z, a, b, c);
    }
    tc[j] = c;
}

// ---------------- fused filter + estimator ----------------

// Compare-swap on (j,v) pairs, ascending j. Named scalars -> registers.
#define CSW(jx, vx, jy, vy) do { \
    int _sw = (jx) > (jy); \
    int _jl = _sw ? (jy) : (jx); int _jh = _sw ? (jx) : (jy); \
    float _vl = _sw ? (vy) : (vx); float _vh = _sw ? (vx) : (vy); \
    (jx) = _jl; (jy) = _jh; (vx) = _vl; (vy) = _vh; } while (0)

__device__ __forceinline__ void bred3(float& x, float& y, float& z, float* red) {
    #pragma unroll
    for (int off = 32; off; off >>= 1) {
        x += __shfl_xor(x, off);
        y += __shfl_xor(y, off);
        z += __shfl_xor(z, off);
    }
    int lane = threadIdx.x & 63, wid = threadIdx.x >> 6;
    if (lane == 0) { red[wid] = x; red[8 + wid] = y; red[16 + wid] = z; }
    __syncthreads();
    x = 0.f; y = 0.f; z = 0.f;
    #pragma unroll
    for (int w = 0; w < 8; ++w) { x += red[w]; y += red[8 + w]; z += red[16 + w]; }
    __syncthreads();
}

__device__ __forceinline__ void bred1(float& x, float* red) {
    #pragma unroll
    for (int off = 32; off; off >>= 1) x += __shfl_xor(x, off);
    int lane = threadIdx.x & 63, wid = threadIdx.x >> 6;
    if (lane == 0) red[wid] = x;
    __syncthreads();
    x = 0.f;
    #pragma unroll
    for (int w = 0; w < 8; ++w) x += red[w];
    __syncthreads();
}

__device__ __forceinline__ void mat3mul(const float* A, const float* B, float* C) {
    #pragma unroll
    for (int r = 0; r < 3; ++r)
        #pragma unroll
        for (int c = 0; c < 3; ++c)
            C[r * 3 + c] = A[r * 3] * B[c] + A[r * 3 + 1] * B[3 + c] + A[r * 3 + 2] * B[6 + c];
}

__device__ __forceinline__ float det3(const float* M) {
    return M[0] * (M[4] * M[8] - M[5] * M[7])
         - M[1] * (M[3] * M[8] - M[5] * M[6])
         + M[2] * (M[3] * M[7] - M[4] * M[6]);
}

__device__ __forceinline__ void powiter3(const float* M, float* v) {
    v[0] = v[1] = v[2] = 0.57735026918962584f;
    for (int it = 0; it < 50; ++it) {
        float y0 = M[0] * v[0] + M[1] * v[1] + M[2] * v[2];
        float y1 = M[3] * v[0] + M[4] * v[1] + M[5] * v[2];
        float y2 = M[6] * v[0] + M[7] * v[1] + M[8] * v[2];
        float n = sqrtf(y0 * y0 + y1 * y1 + y2 * y2) + EPSF;
        v[0] = y0 / n; v[1] = y1 / n; v[2] = y2 / n;
    }
}

__global__ __launch_bounds__(512) void k_final(const float* __restrict__ Kmat,
        const float* __restrict__ tc,
        const int* __restrict__ rowcnt, int* __restrict__ rowj, float* __restrict__ roww,
        float* __restrict__ out)
{
    __shared__ float sW1[NPV];
    __shared__ float sW2[NPV];
    __shared__ int   scnt[NPV];
    __shared__ float red[24];
    __shared__ float sM45[45];
    __shared__ float sMs[81];
    __shared__ float sV9[9];
    __shared__ float sv3[3];
    __shared__ float sKi[9];
    int t = threadIdx.x;

    if (t == 0) {
        float k00 = Kmat[0], k01 = Kmat[1], k02 = Kmat[2];
        float k10 = Kmat[3], k11 = Kmat[4], k12 = Kmat[5];
        float k20 = Kmat[6], k21 = Kmat[7], k22 = Kmat[8];
        float det = k00 * (k11 * k22 - k12 * k21) - k01 * (k10 * k22 - k12 * k20) + k02 * (k10 * k21 - k11 * k20);
        float id = 1.0f / det;
        sKi[0] = (k11 * k22 - k12 * k21) * id; sKi[1] = (k02 * k21 - k01 * k22) * id; sKi[2] = (k01 * k12 - k02 * k11) * id;
        sKi[3] = (k12 * k20 - k10 * k22) * id; sKi[4] = (k00 * k22 - k02 * k20) * id; sKi[5] = (k02 * k10 - k00 * k12) * id;
        sKi[6] = (k10 * k21 - k11 * k20) * id; sKi[7] = (k01 * k20 - k00 * k21) * id; sKi[8] = (k00 * k11 - k01 * k10) * id;
    }
    if (t < 45) sM45[t] = 0.f;
    for (int i = t; i < NPV; i += 512) sW2[i] = 0.f;
    __syncthreads();

    // ---- fused filter: tc test, ascending-j sort (Batcher net), w1, w2 scatter ----
    for (int i = t; i < NPV; i += 512) {
        int n = rowcnt[i]; n = n > 8 ? 8 : n;
        int base = i * 8;
        int j0, j1, j2, j3, j4, j5, j6, j7;
        float v0, v1, v2, v3, v4, v5, v6, v7;
        int m = 0;
#define LD(s, jN, vN) do { \
        int _jj = rowj[base + (s)]; float _vv = roww[base + (s)]; \
        int _in = (s) < n; \
        int _jsafe = _in ? _jj : 0; \
        int _ok = _in && (_vv >= tc[_jsafe]); \
        jN = _ok ? _jj : 0x7FFFFFFF; vN = _ok ? _vv : 0.f; m += _ok; } while (0)
        LD(0, j0, v0); LD(1, j1, v1); LD(2, j2, v2); LD(3, j3, v3);
        LD(4, j4, v4); LD(5, j5, v5); LD(6, j6, v6); LD(7, j7, v7);
#undef LD
        CSW(j0, v0, j1, v1); CSW(j2, v2, j3, v3); CSW(j4, v4, j5, v5); CSW(j6, v6, j7, v7);
        CSW(j0, v0, j2, v2); CSW(j1, v1, j3, v3); CSW(j4, v4, j6, v6); CSW(j5, v5, j7, v7);
        CSW(j1, v1, j2, v2); CSW(j5, v5, j6, v6);
        CSW(j0, v0, j4, v4); CSW(j1, v1, j5, v5); CSW(j2, v2, j6, v6); CSW(j3, v3, j7, v7);
        CSW(j2, v2, j4, v4); CSW(j3, v3, j5, v5);
        CSW(j1, v1, j2, v2); CSW(j3, v3, j4, v4); CSW(j5, v5, j6, v6);
        rowj[base + 0] = j0; rowj[base + 1] = j1; rowj[base + 2] = j2; rowj[base + 3] = j3;
        rowj[base + 4] = j4; rowj[base + 5] = j5; rowj[base + 6] = j6; rowj[base + 7] = j7;
        roww[base + 0] = v0; roww[base + 1] = v1; roww[base + 2] = v2; roww[base + 3] = v3;
        roww[base + 4] = v4; roww[base + 5] = v5; roww[base + 6] = v6; roww[base + 7] = v7;
        scnt[i] = m;
        sW1[i] = ((((((v0 + v1) + v2) + v3) + v4) + v5) + v6) + v7;
        if (v0 != 0.f) atomicAdd(&sW2[j0], v0);
        if (v1 != 0.f) atomicAdd(&sW2[j1], v1);
        if (v2 != 0.f) atomicAdd(&sW2[j2], v2);
        if (v3 != 0.f) atomicAdd(&sW2[j3], v3);
        if (v4 != 0.f) atomicAdd(&sW2[j4], v4);
        if (v5 != 0.f) atomicAdd(&sW2[j5], v5);
        if (v6 != 0.f) atomicAdd(&sW2[j6], v6);
        if (v7 != 0.f) atomicAdd(&sW2[j7], v7);
    }
    __syncthreads();

    auto PX = [&](int i) -> float {
        float x = (float)(i & 63), y = (float)(i >> 6);
        return sKi[0] * x + sKi[1] * y + sKi[2];
    };
    auto PY = [&](int i) -> float {
        float x = (float)(i & 63), y = (float)(i >> 6);
        return sKi[3] * x + sKi[4] * y + sKi[5];
    };

    // ---- Hartley normalization, both sets ----
    float cc[2][2], ssH[2];
    #pragma unroll
    for (int set = 0; set < 2; ++set) {
        float sw = 0.f, sx = 0.f, sy = 0.f;
        for (int i = t; i < NPV; i += 512) {
            float w = set ? sW2[i] : sW1[i];
            sw += w; sx += w * PX(i); sy += w * PY(i);
        }
        bred3(sw, sx, sy, red);
        float ws = sw + EPSF;
        float cx = sx / ws, cy = sy / ws;
        float smd = 0.f;
        for (int i = t; i < NPV; i += 512) {
            float w = set ? sW2[i] : sW1[i];
            float dx = PX(i) - cx, dy = PY(i) - cy;
            smd += w * (dx * dx + dy * dy);
        }
        bred1(smd, red);
        float md = sqrtf(smd / ws + EPSF);
        cc[set][0] = cx; cc[set][1] = cy;
        ssH[set] = 1.4142135623730951f / (md + EPSF);
    }
    float c1x = cc[0][0], c1y = cc[0][1], s1 = ssH[0];
    float c2x = cc[1][0], c2y = cc[1][1], s2 = ssH[1];

    // ---- 9x9 moment matrix (45 unique entries), LDS-atomic reduce ----
    {
        float acc[45];
        #pragma unroll
        for (int k = 0; k < 45; ++k) acc[k] = 0.f;
        for (int i = t; i < NPV; i += 512) {
            int n = scnt[i];
            if (n == 0) continue;
            float f1x = (PX(i) - c1x) * s1;
            float f1y = (PY(i) - c1y) * s1;
            for (int e = 0; e < n; ++e) {
                int j = rowj[i * 8 + e];
                float w = roww[i * 8 + e];
                float f2x = (PX(j) - c2x) * s2;
                float f2y = (PY(j) - c2y) * s2;
                float a[9];
                a[0] = f1x * f2x; a[1] = f1x * f2y; a[2] = f1x;
                a[3] = f1y * f2x; a[4] = f1y * f2y; a[5] = f1y;
                a[6] = f2x;       a[7] = f2y;       a[8] = 1.f;
                int idx = 0;
                #pragma unroll
                for (int u = 0; u < 9; ++u) {
                    float wa = w * a[u];
                    #pragma unroll
                    for (int v = u; v < 9; ++v) { acc[idx] = fmaf(wa, a[v], acc[idx]); ++idx; }
                }
            }
        }
        #pragma unroll
        for (int k = 0; k < 45; ++k)
            if (acc[k] != 0.f) atomicAdd(&sM45[k], acc[k]);
    }
    __syncthreads();

    if (t == 0) {
        float M[81];
        int idx = 0;
        for (int u = 0; u < 9; ++u)
            for (int v = u; v < 9; ++v) {
                float s = sM45[idx];
                M[u * 9 + v] = s; M[v * 9 + u] = s;
                ++idx;
            }
        float lam = 0.f;
        for (int d = 0; d < 9; ++d) lam += M[d * 9 + d];
        for (int r = 0; r < 9; ++r)
            for (int c = 0; c < 9; ++c)
                sMs[r * 9 + c] = (r == c ? lam : 0.f) - M[r * 9 + c];
    }
    __syncthreads();

    // ---- 50-iter 9x9 power method, wave 0 ----
    if (t < 64) {
        float mrow[9];
        #pragma unroll
        for (int c = 0; c < 9; ++c) mrow[c] = (t < 9) ? sMs[t * 9 + c] : 0.f;
        float v = (t < 9) ? (1.f / 3.f) : 0.f;
        for (int it = 0; it < 50; ++it) {
            float y = 0.f;
            #pragma unroll
            for (int c = 0; c < 9; ++c) y = fmaf(mrow[c], __shfl(v, c, 64), y);
            float q = (t < 9) ? y * y : 0.f;
            q += __shfl_xor(q, 1);
            q += __shfl_xor(q, 2);
            q += __shfl_xor(q, 4);
            q += __shfl_xor(q, 8);
            float n = sqrtf(q) + EPSF;
            v = y / n;
        }
        if (t < 9) sV9[t] = v;
    }
    __syncthreads();

    // ---- 3x3 tail: v1 on t=0, v3 on t=64 (concurrent waves) ----
    float Ee[9], B[9], v1l[3];
    if (t == 0 || t == 64) {
        float Er[9];
        #pragma unroll
        for (int k = 0; k < 9; ++k) Er[k] = sV9[k];
        float T1[9]  = { s1, 0.f, -s1 * c1x,   0.f, s1, -s1 * c1y,   0.f, 0.f, 1.f };
        float T2t[9] = { s2, 0.f, 0.f,   0.f, s2, 0.f,   -s2 * c2x, -s2 * c2y, 1.f };
        float M1[9];
        mat3mul(Er, T1, M1);
        mat3mul(T2t, M1, Ee);
        #pragma unroll
        for (int r = 0; r < 3; ++r)
            #pragma unroll
            for (int c = 0; c < 3; ++c)
                B[r * 3 + c] = Ee[r] * Ee[c] + Ee[3 + r] * Ee[3 + c] + Ee[6 + r] * Ee[6 + c];
        if (t == 0) {
            powiter3(B, v1l);
        } else {
            float lam3 = B[0] + B[4] + B[8];
            float Bs[9];
            #pragma unroll
            for (int k = 0; k < 9; ++k) Bs[k] = -B[k];
            Bs[0] += lam3; Bs[4] += lam3; Bs[8] += lam3;
            float v3l[3];
            powiter3(Bs, v3l);
            sv3[0] = v3l[0]; sv3[1] = v3l[1]; sv3[2] = v3l[2];
        }
    }
    __syncthreads();

    if (t == 0) {
        float v1[3] = { v1l[0], v1l[1], v1l[2] };
        float v3[3] = { sv3[0], sv3[1], sv3[2] };
        float v2[3];
        v2[0] = v3[1] * v1[2] - v3[2] * v1[1];
        v2[1] = v3[2] * v1[0] - v3[0] * v1[2];
        v2[2] = v3[0] * v1[1] - v3[1] * v1[0];
        float n2 = sqrtf(v2[0] * v2[0] + v2[1] * v2[1] + v2[2] * v2[2]) + EPSF;
        v2[0] /= n2; v2[1] /= n2; v2[2] /= n2;
        float V[9];
        #pragma unroll
        for (int r = 0; r < 3; ++r) { V[r * 3 + 0] = v1[r]; V[r * 3 + 1] = v2[r]; V[r * 3 + 2] = v3[r]; }
        float dV = det3(V);
        float sV = (dV > 0.f) ? 1.f : ((dV < 0.f) ? -1.f : 0.f);
        V[2] *= sV; V[5] *= sV; V[8] *= sV;
        float Ev1[3], Ev2[3];
        #pragma unroll
        for (int r = 0; r < 3; ++r) {
            Ev1[r] = Ee[r * 3] * V[0] + Ee[r * 3 + 1] * V[3] + Ee[r * 3 + 2] * V[6];
            Ev2[r] = Ee[r * 3] * V[1] + Ee[r * 3 + 1] * V[4] + Ee[r * 3 + 2] * V[7];
        }
        float s1n = sqrtf(Ev1[0] * Ev1[0] + Ev1[1] * Ev1[1] + Ev1[2] * Ev1[2]);
        float s2n = sqrtf(Ev2[0] * Ev2[0] + Ev2[1] * Ev2[1] + Ev2[2] * Ev2[2]);
        float s_avg = (s1n + s2n) * 0.5f;
        float u1[3], u2[3];
        #pragma unroll
        for (int r = 0; r < 3; ++r) { u1[r] = Ev1[r] / (s1n + EPSF); u2[r] = Ev2[r] / (s2n + EPSF); }
        #pragma unroll
        for (int r = 0; r < 3; ++r)
            #pragma unroll
            for (int c = 0; c < 3; ++c)
                out[r * 3 + c] = s_avg * (u1[r] * V[c * 3 + 0] + u2[r] * V[c * 3 + 1]);
    }
}

extern "C" void kernel_launch(void* const* d_in, const int* in_sizes, int n_in,
                              void* d_out, int out_size, void* d_ws, size_t ws_size,
                              hipStream_t stream)
{
    const float* P = (const float*)d_in[0];
    const float* K = (const float*)d_in[1];
    float* out = (float*)d_out;

    float* fws    = (float*)d_ws;
    float* tr     = fws;                      // N
    float* tc     = tr + NPV;                 // N
    float* roww   = tc + NPV;                 // 8N
    int*   rowj   = (int*)(roww + 8 * NPV);   // 8N
    int*   rowcnt = rowj + 8 * NPV;           // N
    float* part   = (float*)(rowcnt + NPV);   // 3N * nseg

    size_t fixed_bytes = (size_t)NPV * 19 * sizeof(float);
    int nseg = 16;
    for (int cand = 128; cand >= 16; cand >>= 1) {
        if (ws_size >= fixed_bytes + (size_t)cand * NPV * 3 * sizeof(float)) { nseg = cand; break; }
    }
    int segrows = NPV / nseg;

    k_row_top3<<<NPV / 4, 256, 0, stream>>>(P, tr, rowcnt);
    dim3 g2(NPV / 256, nseg);
    k_col_pass<<<g2, 256, 0, stream>>>(P, tr, part, segrows, rowcnt, rowj, roww);
    k_col_merge<<<NPV / 64, 64, 0, stream>>>(part, tc, nseg);
    k_final<<<1, 512, 0, stream>>>(K, tc, rowcnt, rowj, roww, out);
}

// Round 5
// 119.216 us; speedup vs baseline: 1.9062x; 1.9062x over previous
//
#include <hip/hip_runtime.h>
#include <math.h>

#define NPV 3072
#define LDP 3073
#define EPSF 1e-8f

// Branchless insert of v into sorted-descending triple (a >= b >= c).
#define INS3(v, a, b, c) do { \
    float _m1 = fminf((a), (v)); (a) = fmaxf((a), (v)); \
    float _m2 = fminf((b), _m1); (b) = fmaxf((b), _m1); \
    (c) = fmaxf((c), _m2); } while (0)

#define MRG3(x, y, z, a, b, c) do { \
    INS3((x), a, b, c); INS3((y), a, b, c); INS3((z), a, b, c); } while (0)

// One wave per row (4 rows/block), branchless values-only top-3.
__global__ __launch_bounds__(256) void k_row_top3(const float* __restrict__ P,
        float* __restrict__ tr, int* __restrict__ rowcnt)
{
    int lane = threadIdx.x & 63;
    int i = blockIdx.x * 4 + (threadIdx.x >> 6);
    const float* row = P + (size_t)i * LDP;
    float a0 = -1e30f, b0 = -1e30f, c0 = -1e30f;
    float a1 = -1e30f, b1 = -1e30f, c1 = -1e30f;
    float a2 = -1e30f, b2 = -1e30f, c2 = -1e30f;
    float a3 = -1e30f, b3 = -1e30f, c3 = -1e30f;
    #pragma unroll
    for (int r = 0; r < 48; r += 4) {
        float v0 = row[(r + 0) * 64 + lane];
        float v1 = row[(r + 1) * 64 + lane];
        float v2 = row[(r + 2) * 64 + lane];
        float v3 = row[(r + 3) * 64 + lane];
        INS3(v0, a0, b0, c0);
        INS3(v1, a1, b1, c1);
        INS3(v2, a2, b2, c2);
        INS3(v3, a3, b3, c3);
    }
    MRG3(a1, b1, c1, a0, b0, c0);
    MRG3(a2, b2, c2, a0, b0, c0);
    MRG3(a3, b3, c3, a0, b0, c0);
    #pragma unroll
    for (int off = 1; off < 64; off <<= 1) {
        float xa = __shfl_xor(a0, off);
        float xb = __shfl_xor(b0, off);
        float xc = __shfl_xor(c0, off);
        MRG3(xa, xb, xc, a0, b0, c0);
    }
    if (lane == 0) { tr[i] = c0; rowcnt[i] = 0; }
}

#define CAND(v, i) do { \
    if ((v) >= tr[i] && (v) > 0.01f) { \
        int _s = atomicAdd(&rowcnt[i], 1); \
        if (_s < 8) { rowj[(size_t)(i) * 8 + _s] = j; roww[(size_t)(i) * 8 + _s] = (v); } \
    } } while (0)

__global__ __launch_bounds__(256) void k_col_pass(const float* __restrict__ P,
        const float* __restrict__ tr, float* __restrict__ part, int segrows,
        int* __restrict__ rowcnt, int* __restrict__ rowj, float* __restrict__ roww)
{
    int j = blockIdx.x * 256 + threadIdx.x;
    int i0 = blockIdx.y * segrows;
    float a0 = -1e30f, b0 = -1e30f, c0 = -1e30f;
    float a1 = -1e30f, b1 = -1e30f, c1 = -1e30f;
    float a2 = -1e30f, b2 = -1e30f, c2 = -1e30f;
    float a3 = -1e30f, b3 = -1e30f, c3 = -1e30f;
    float a4 = -1e30f, b4 = -1e30f, c4 = -1e30f;
    float a5 = -1e30f, b5 = -1e30f, c5 = -1e30f;
    float a6 = -1e30f, b6 = -1e30f, c6 = -1e30f;
    float a7 = -1e30f, b7 = -1e30f, c7 = -1e30f;
    for (int r = 0; r < segrows; r += 8) {
        int i = i0 + r;
        const float* col = P + (size_t)i * LDP + j;
        float v0 = col[0 * LDP];
        float v1 = col[1 * LDP];
        float v2 = col[2 * LDP];
        float v3 = col[3 * LDP];
        float v4 = col[4 * LDP];
        float v5 = col[5 * LDP];
        float v6 = col[6 * LDP];
        float v7 = col[7 * LDP];
        INS3(v0, a0, b0, c0);
        INS3(v1, a1, b1, c1);
        INS3(v2, a2, b2, c2);
        INS3(v3, a3, b3, c3);
        INS3(v4, a4, b4, c4);
        INS3(v5, a5, b5, c5);
        INS3(v6, a6, b6, c6);
        INS3(v7, a7, b7, c7);
        CAND(v0, i + 0);
        CAND(v1, i + 1);
        CAND(v2, i + 2);
        CAND(v3, i + 3);
        CAND(v4, i + 4);
        CAND(v5, i + 5);
        CAND(v6, i + 6);
        CAND(v7, i + 7);
    }
    MRG3(a1, b1, c1, a0, b0, c0);
    MRG3(a2, b2, c2, a0, b0, c0);
    MRG3(a3, b3, c3, a0, b0, c0);
    MRG3(a4, b4, c4, a0, b0, c0);
    MRG3(a5, b5, c5, a0, b0, c0);
    MRG3(a6, b6, c6, a0, b0, c0);
    MRG3(a7, b7, c7, a0, b0, c0);
    size_t o = ((size_t)blockIdx.y * NPV + j) * 3;
    part[o] = a0; part[o + 1] = b0; part[o + 2] = c0;
}

__global__ __launch_bounds__(64) void k_col_merge(const float* __restrict__ part,
        float* __restrict__ tc, int nseg)
{
    int j = blockIdx.x * 64 + threadIdx.x;
    float a = -1e30f, b = -1e30f, c = -1e30f;
    for (int s = 0; s < nseg; ++s) {
        size_t o = ((size_t)s * NPV + j) * 3;
        float x = part[o], y = part[o + 1], z = part[o + 2];
        MRG3(x, y, z, a, b, c);
    }
    tc[j] = c;
}

// ---------------- fused filter + estimator (single block, 512 threads) ----------------

#define CSW(jx, vx, jy, vy) do { \
    int _sw = (jx) > (jy); \
    int _jl = _sw ? (jy) : (jx); int _jh = _sw ? (jx) : (jy); \
    float _vl = _sw ? (vy) : (vx); float _vh = _sw ? (vx) : (vy); \
    (jx) = _jl; (jy) = _jh; (vx) = _vl; (vy) = _vh; } while (0)

// 8-value block reduce: butterfly within wave + one LDS combine. All threads
// end with the block-wide sums in s[0..7]. red must hold 64 floats.
__device__ __forceinline__ void bred8(float* s, float* red) {
    #pragma unroll
    for (int off = 32; off; off >>= 1)
        #pragma unroll
        for (int k = 0; k < 8; ++k) s[k] += __shfl_xor(s[k], off);
    int lane = threadIdx.x & 63, wid = threadIdx.x >> 6;
    if (lane == 0) {
        #pragma unroll
        for (int k = 0; k < 8; ++k) red[wid * 8 + k] = s[k];
    }
    __syncthreads();
    #pragma unroll
    for (int k = 0; k < 8; ++k) {
        float acc = 0.f;
        #pragma unroll
        for (int w = 0; w < 8; ++w) acc += red[w * 8 + k];
        s[k] = acc;
    }
    __syncthreads();
}

__device__ __forceinline__ void mat3mul(const float* A, const float* B, float* C) {
    #pragma unroll
    for (int r = 0; r < 3; ++r)
        #pragma unroll
        for (int c = 0; c < 3; ++c)
            C[r * 3 + c] = A[r * 3] * B[c] + A[r * 3 + 1] * B[3 + c] + A[r * 3 + 2] * B[6 + c];
}

__device__ __forceinline__ float det3(const float* M) {
    return M[0] * (M[4] * M[8] - M[5] * M[7])
         - M[1] * (M[3] * M[8] - M[5] * M[6])
         + M[2] * (M[3] * M[7] - M[4] * M[6]);
}

__device__ __forceinline__ void powiter3(const float* M, float* v) {
    v[0] = v[1] = v[2] = 0.57735026918962584f;
    for (int it = 0; it < 50; ++it) {
        float y0 = M[0] * v[0] + M[1] * v[1] + M[2] * v[2];
        float y1 = M[3] * v[0] + M[4] * v[1] + M[5] * v[2];
        float y2 = M[6] * v[0] + M[7] * v[1] + M[8] * v[2];
        float n = sqrtf(y0 * y0 + y1 * y1 + y2 * y2) + EPSF;
        v[0] = y0 / n; v[1] = y1 / n; v[2] = y2 / n;
    }
}

__global__ __launch_bounds__(512) void k_final(const float* __restrict__ Kmat,
        const float* __restrict__ tc,
        const int* __restrict__ rowcnt, const int* __restrict__ rowj,
        const float* __restrict__ roww, float* __restrict__ out)
{
    __shared__ float sW2[NPV];
    __shared__ float red[64];
    __shared__ float sMred[8 * 45];
    __shared__ float sM45[45];
    __shared__ float sMs[81];
    __shared__ float sV9[9];
    __shared__ float sv3[3];
    int t = threadIdx.x;

    // K inverse, redundantly per-thread (Kmat[..] broadcasts; no barrier needed).
    float ki0, ki1, ki2, ki3, ki4, ki5;
    {
        float k00 = Kmat[0], k01 = Kmat[1], k02 = Kmat[2];
        float k10 = Kmat[3], k11 = Kmat[4], k12 = Kmat[5];
        float k20 = Kmat[6], k21 = Kmat[7], k22 = Kmat[8];
        float det = k00 * (k11 * k22 - k12 * k21) - k01 * (k10 * k22 - k12 * k20) + k02 * (k10 * k21 - k11 * k20);
        float id = 1.0f / det;
        ki0 = (k11 * k22 - k12 * k21) * id; ki1 = (k02 * k21 - k01 * k22) * id; ki2 = (k01 * k12 - k02 * k11) * id;
        ki3 = (k12 * k20 - k10 * k22) * id; ki4 = (k00 * k22 - k02 * k20) * id; ki5 = (k02 * k10 - k00 * k12) * id;
    }
#define PXI(i) (ki0 * (float)((i) & 63) + ki1 * (float)((i) >> 6) + ki2)
#define PYI(i) (ki3 * (float)((i) & 63) + ki4 * (float)((i) >> 6) + ki5)

    #pragma unroll
    for (int k = 0; k < 6; ++k) sW2[t + 512 * k] = 0.f;
    __syncthreads();

    // ---- Phase A: load 6 own rows' candidates, filter by tc, sort asc-j, keep in regs ----
    int   jj[6][8];
    float vv[6][8];
    float w1r[6];
    #pragma unroll
    for (int r = 0; r < 6; ++r) {
        int i = t * 6 + r;
        int n = rowcnt[i]; n = n > 8 ? 8 : n;
        int4  ja = ((const int4*)(rowj + (size_t)i * 8))[0];
        int4  jb = ((const int4*)(rowj + (size_t)i * 8))[1];
        float4 va = ((const float4*)(roww + (size_t)i * 8))[0];
        float4 vb = ((const float4*)(roww + (size_t)i * 8))[1];
        int j0, j1, j2, j3, j4, j5, j6, j7;
        float v0, v1, v2, v3, v4, v5, v6, v7;
#define LD(s, jraw, vraw, jN, vN) do { \
        int _in = (s) < n; \
        int _jsafe = _in ? (jraw) : 0; \
        int _ok = _in && ((vraw) >= tc[_jsafe]); \
        jN = _ok ? (jraw) : 0x7FFFFFFF; vN = _ok ? (vraw) : 0.f; } while (0)
        LD(0, ja.x, va.x, j0, v0); LD(1, ja.y, va.y, j1, v1);
        LD(2, ja.z, va.z, j2, v2); LD(3, ja.w, va.w, j3, v3);
        LD(4, jb.x, vb.x, j4, v4); LD(5, jb.y, vb.y, j5, v5);
        LD(6, jb.z, vb.z, j6, v6); LD(7, jb.w, vb.w, j7, v7);
#undef LD
        CSW(j0, v0, j1, v1); CSW(j2, v2, j3, v3); CSW(j4, v4, j5, v5); CSW(j6, v6, j7, v7);
        CSW(j0, v0, j2, v2); CSW(j1, v1, j3, v3); CSW(j4, v4, j6, v6); CSW(j5, v5, j7, v7);
        CSW(j1, v1, j2, v2); CSW(j5, v5, j6, v6);
        CSW(j0, v0, j4, v4); CSW(j1, v1, j5, v5); CSW(j2, v2, j6, v6); CSW(j3, v3, j7, v7);
        CSW(j2, v2, j4, v4); CSW(j3, v3, j5, v5);
        CSW(j1, v1, j2, v2); CSW(j3, v3, j4, v4); CSW(j5, v5, j6, v6);
        jj[r][0] = j0; jj[r][1] = j1; jj[r][2] = j2; jj[r][3] = j3;
        jj[r][4] = j4; jj[r][5] = j5; jj[r][6] = j6; jj[r][7] = j7;
        vv[r][0] = v0; vv[r][1] = v1; vv[r][2] = v2; vv[r][3] = v3;
        vv[r][4] = v4; vv[r][5] = v5; vv[r][6] = v6; vv[r][7] = v7;
        w1r[r] = ((((((v0 + v1) + v2) + v3) + v4) + v5) + v6) + v7;
        if (v0 > 0.f) atomicAdd(&sW2[j0], v0);
        if (v1 > 0.f) atomicAdd(&sW2[j1], v1);
        if (v2 > 0.f) atomicAdd(&sW2[j2], v2);
        if (v3 > 0.f) atomicAdd(&sW2[j3], v3);
        if (v4 > 0.f) atomicAdd(&sW2[j4], v4);
        if (v5 > 0.f) atomicAdd(&sW2[j5], v5);
        if (v6 > 0.f) atomicAdd(&sW2[j6], v6);
        if (v7 > 0.f) atomicAdd(&sW2[j7], v7);
    }
    __syncthreads();

    // ---- Phase B: one-pass Hartley moments for both sets; one block reduce ----
    float s8[8];
    #pragma unroll
    for (int k = 0; k < 8; ++k) s8[k] = 0.f;
    #pragma unroll
    for (int r = 0; r < 6; ++r) {
        int i = t * 6 + r;
        float w = w1r[r];
        float px = PXI(i), py = PYI(i);
        s8[0] += w; s8[1] += w * px; s8[2] += w * py; s8[3] += w * (px * px + py * py);
        int i2 = t + 512 * r;
        float w2 = sW2[i2];
        float qx = PXI(i2), qy = PYI(i2);
        s8[4] += w2; s8[5] += w2 * qx; s8[6] += w2 * qy; s8[7] += w2 * (qx * qx + qy * qy);
    }
    bred8(s8, red);
    float ws1 = s8[0] + EPSF, ws2 = s8[4] + EPSF;
    float c1x = s8[1] / ws1, c1y = s8[2] / ws1;
    float c2x = s8[5] / ws2, c2y = s8[6] / ws2;
    float md1 = sqrtf((s8[3] - 2.f * (c1x * s8[1] + c1y * s8[2]) + (c1x * c1x + c1y * c1y) * s8[0]) / ws1 + EPSF);
    float md2 = sqrtf((s8[7] - 2.f * (c2x * s8[5] + c2y * s8[6]) + (c2x * c2x + c2y * c2y) * s8[4]) / ws2 + EPSF);
    float s1 = 1.4142135623730951f / (md1 + EPSF);
    float s2 = 1.4142135623730951f / (md2 + EPSF);

    // ---- Phase C: 9x9 moment matrix from registers ----
    {
        float acc[45];
        #pragma unroll
        for (int k = 0; k < 45; ++k) acc[k] = 0.f;
        #pragma unroll
        for (int r = 0; r < 6; ++r) {
            int i = t * 6 + r;
            float f1x = (PXI(i) - c1x) * s1;
            float f1y = (PYI(i) - c1y) * s1;
            #pragma unroll
            for (int e = 0; e < 8; ++e) {
                float w = vv[r][e];
                if (w > 0.f) {
                    int j = jj[r][e];
                    float f2x = (PXI(j) - c2x) * s2;
                    float f2y = (PYI(j) - c2y) * s2;
                    float a[9];
                    a[0] = f1x * f2x; a[1] = f1x * f2y; a[2] = f1x;
                    a[3] = f1y * f2x; a[4] = f1y * f2y; a[5] = f1y;
                    a[6] = f2x;       a[7] = f2y;       a[8] = 1.f;
                    int idx = 0;
                    #pragma unroll
                    for (int u = 0; u < 9; ++u) {
                        float wa = w * a[u];
                        #pragma unroll
                        for (int v = u; v < 9; ++v) { acc[idx] = fmaf(wa, a[v], acc[idx]); ++idx; }
                    }
                }
            }
        }
        int lane = t & 63, wid = t >> 6;
        #pragma unroll
        for (int k = 0; k < 45; ++k) {
            float v = acc[k];
            #pragma unroll
            for (int off = 32; off; off >>= 1) v += __shfl_xor(v, off);
            if (lane == 0) sMred[wid * 45 + k] = v;
        }
    }
    __syncthreads();
    if (t < 45) {
        float s = 0.f;
        #pragma unroll
        for (int w = 0; w < 8; ++w) s += sMred[w * 45 + t];
        sM45[t] = s;
    }
    __syncthreads();
    if (t == 0) {
        float M[81];
        int idx = 0;
        for (int u = 0; u < 9; ++u)
            for (int v = u; v < 9; ++v) {
                float s = sM45[idx];
                M[u * 9 + v] = s; M[v * 9 + u] = s;
                ++idx;
            }
        float lam = 0.f;
        for (int d = 0; d < 9; ++d) lam += M[d * 9 + d];
        for (int r = 0; r < 9; ++r)
            for (int c = 0; c < 9; ++c)
                sMs[r * 9 + c] = (r == c ? lam : 0.f) - M[r * 9 + c];
    }
    __syncthreads();

    // ---- Phase D: 50-iter 9x9 power method on wave 0 ----
    if (t < 64) {
        float mrow[9];
        #pragma unroll
        for (int c = 0; c < 9; ++c) mrow[c] = (t < 9) ? sMs[t * 9 + c] : 0.f;
        float v = (t < 9) ? (1.f / 3.f) : 0.f;
        for (int it = 0; it < 50; ++it) {
            float y = 0.f;
            #pragma unroll
            for (int c = 0; c < 9; ++c) y = fmaf(mrow[c], __shfl(v, c, 64), y);
            float q = (t < 9) ? y * y : 0.f;
            q += __shfl_xor(q, 1);
            q += __shfl_xor(q, 2);
            q += __shfl_xor(q, 4);
            q += __shfl_xor(q, 8);
            float n = sqrtf(q) + EPSF;
            v = y / n;
        }
        if (t < 9) sV9[t] = v;
    }
    __syncthreads();

    // ---- Phase E: 3x3 tail, v1 on t=0 and v3 on t=64 concurrently ----
    float Ee[9], B[9], v1l[3];
    if (t == 0 || t == 64) {
        float Er[9];
        #pragma unroll
        for (int k = 0; k < 9; ++k) Er[k] = sV9[k];
        float T1[9]  = { s1, 0.f, -s1 * c1x,   0.f, s1, -s1 * c1y,   0.f, 0.f, 1.f };
        float T2t[9] = { s2, 0.f, 0.f,   0.f, s2, 0.f,   -s2 * c2x, -s2 * c2y, 1.f };
        float M1[9];
        mat3mul(Er, T1, M1);
        mat3mul(T2t, M1, Ee);
        #pragma unroll
        for (int r = 0; r < 3; ++r)
            #pragma unroll
            for (int c = 0; c < 3; ++c)
                B[r * 3 + c] = Ee[r] * Ee[c] + Ee[3 + r] * Ee[3 + c] + Ee[6 + r] * Ee[6 + c];
        if (t == 0) {
            powiter3(B, v1l);
        } else {
            float lam3 = B[0] + B[4] + B[8];
            float Bs[9];
            #pragma unroll
            for (int k = 0; k < 9; ++k) Bs[k] = -B[k];
            Bs[0] += lam3; Bs[4] += lam3; Bs[8] += lam3;
            float v3l[3];
            powiter3(Bs, v3l);
            sv3[0] = v3l[0]; sv3[1] = v3l[1]; sv3[2] = v3l[2];
        }
    }
    __syncthreads();

    if (t == 0) {
        float v1[3] = { v1l[0], v1l[1], v1l[2] };
        float v3[3] = { sv3[0], sv3[1], sv3[2] };
        float v2[3];
        v2[0] = v3[1] * v1[2] - v3[2] * v1[1];
        v2[1] = v3[2] * v1[0] - v3[0] * v1[2];
        v2[2] = v3[0] * v1[1] - v3[1] * v1[0];
        float n2 = sqrtf(v2[0] * v2[0] + v2[1] * v2[1] + v2[2] * v2[2]) + EPSF;
        v2[0] /= n2; v2[1] /= n2; v2[2] /= n2;
        float V[9];
        #pragma unroll
        for (int r = 0; r < 3; ++r) { V[r * 3 + 0] = v1[r]; V[r * 3 + 1] = v2[r]; V[r * 3 + 2] = v3[r]; }
        float dV = det3(V);
        float sV = (dV > 0.f) ? 1.f : ((dV < 0.f) ? -1.f : 0.f);
        V[2] *= sV; V[5] *= sV; V[8] *= sV;
        float Ev1[3], Ev2[3];
        #pragma unroll
        for (int r = 0; r < 3; ++r) {
            Ev1[r] = Ee[r * 3] * V[0] + Ee[r * 3 + 1] * V[3] + Ee[r * 3 + 2] * V[6];
            Ev2[r] = Ee[r * 3] * V[1] + Ee[r * 3 + 1] * V[4] + Ee[r * 3 + 2] * V[7];
        }
        float s1n = sqrtf(Ev1[0] * Ev1[0] + Ev1[1] * Ev1[1] + Ev1[2] * Ev1[2]);
        float s2n = sqrtf(Ev2[0] * Ev2[0] + Ev2[1] * Ev2[1] + Ev2[2] * Ev2[2]);
        float s_avg = (s1n + s2n) * 0.5f;
        float u1[3], u2[3];
        #pragma unroll
        for (int r = 0; r < 3; ++r) { u1[r] = Ev1[r] / (s1n + EPSF); u2[r] = Ev2[r] / (s2n + EPSF); }
        #pragma unroll
        for (int r = 0; r < 3; ++r)
            #pragma unroll
            for (int c = 0; c < 3; ++c)
                out[r * 3 + c] = s_avg * (u1[r] * V[c * 3 + 0] + u2[r] * V[c * 3 + 1]);
    }
}

extern "C" void kernel_launch(void* const* d_in, const int* in_sizes, int n_in,
                              void* d_out, int out_size, void* d_ws, size_t ws_size,
                              hipStream_t stream)
{
    const float* P = (const float*)d_in[0];
    const float* K = (const float*)d_in[1];
    float* out = (float*)d_out;

    float* fws    = (float*)d_ws;
    float* tr     = fws;                      // N
    float* tc     = tr + NPV;                 // N
    float* roww   = tc + NPV;                 // 8N
    int*   rowj   = (int*)(roww + 8 * NPV);   // 8N
    int*   rowcnt = rowj + 8 * NPV;           // N
    float* part   = (float*)(rowcnt + NPV);   // 3N * nseg

    size_t fixed_bytes = (size_t)NPV * 19 * sizeof(float);
    int nseg = 16;
    for (int cand = 128; cand >= 16; cand >>= 1) {
        if (ws_size >= fixed_bytes + (size_t)cand * NPV * 3 * sizeof(float)) { nseg = cand; break; }
    }
    int segrows = NPV / nseg;

    k_row_top3<<<NPV / 4, 256, 0, stream>>>(P, tr, rowcnt);
    dim3 g2(NPV / 256, nseg);
    k_col_pass<<<g2, 256, 0, stream>>>(P, tr, part, segrows, rowcnt, rowj, roww);
    k_col_merge<<<NPV / 64, 64, 0, stream>>>(part, tc, nseg);
    k_final<<<1, 512, 0, stream>>>(K, tc, rowcnt, rowj, roww, out);
}

// Round 6
// 93.633 us; speedup vs baseline: 2.4270x; 1.2732x over previous
//
#include <hip/hip_runtime.h>
#include <math.h>

#define NPV 3072
#define LDP 3073
#define EPSF 1e-8f
#define NMOM 52   // [0..6] w-moments (Sw, Sx1,Sy1,Sq1, Sx2,Sy2,Sq2), [7..51] 45 sym tensor

// Branchless insert of v into sorted-descending triple (a >= b >= c).
#define INS3(v, a, b, c) do { \
    float _m1 = fminf((a), (v)); (a) = fmaxf((a), (v)); \
    float _m2 = fminf((b), _m1); (b) = fmaxf((b), _m1); \
    (c) = fmaxf((c), _m2); } while (0)

#define MRG3(x, y, z, a, b, c) do { \
    INS3((x), a, b, c); INS3((y), a, b, c); INS3((z), a, b, c); } while (0)

__device__ __forceinline__ void kinv6(const float* __restrict__ Kmat,
        float& ki0, float& ki1, float& ki2, float& ki3, float& ki4, float& ki5)
{
    float k00 = Kmat[0], k01 = Kmat[1], k02 = Kmat[2];
    float k10 = Kmat[3], k11 = Kmat[4], k12 = Kmat[5];
    float k20 = Kmat[6], k21 = Kmat[7], k22 = Kmat[8];
    float det = k00 * (k11 * k22 - k12 * k21) - k01 * (k10 * k22 - k12 * k20) + k02 * (k10 * k21 - k11 * k20);
    float id = 1.0f / det;
    ki0 = (k11 * k22 - k12 * k21) * id; ki1 = (k02 * k21 - k01 * k22) * id; ki2 = (k01 * k12 - k02 * k11) * id;
    ki3 = (k12 * k20 - k10 * k22) * id; ki4 = (k00 * k22 - k02 * k20) * id; ki5 = (k02 * k10 - k00 * k12) * id;
}

// One wave per row (4 rows/block), branchless values-only top-3.
// Block 0 also zeroes the 52-float moment accumulator.
__global__ __launch_bounds__(256) void k_row_top3(const float* __restrict__ P,
        float* __restrict__ tr, int* __restrict__ rowcnt, float* __restrict__ mom)
{
    if (blockIdx.x == 0 && threadIdx.x < NMOM) mom[threadIdx.x] = 0.f;
    int lane = threadIdx.x & 63;
    int i = blockIdx.x * 4 + (threadIdx.x >> 6);
    const float* row = P + (size_t)i * LDP;
    float a0 = -1e30f, b0 = -1e30f, c0 = -1e30f;
    float a1 = -1e30f, b1 = -1e30f, c1 = -1e30f;
    float a2 = -1e30f, b2 = -1e30f, c2 = -1e30f;
    float a3 = -1e30f, b3 = -1e30f, c3 = -1e30f;
    #pragma unroll
    for (int r = 0; r < 48; r += 4) {
        float v0 = row[(r + 0) * 64 + lane];
        float v1 = row[(r + 1) * 64 + lane];
        float v2 = row[(r + 2) * 64 + lane];
        float v3 = row[(r + 3) * 64 + lane];
        INS3(v0, a0, b0, c0);
        INS3(v1, a1, b1, c1);
        INS3(v2, a2, b2, c2);
        INS3(v3, a3, b3, c3);
    }
    MRG3(a1, b1, c1, a0, b0, c0);
    MRG3(a2, b2, c2, a0, b0, c0);
    MRG3(a3, b3, c3, a0, b0, c0);
    #pragma unroll
    for (int off = 1; off < 64; off <<= 1) {
        float xa = __shfl_xor(a0, off);
        float xb = __shfl_xor(b0, off);
        float xc = __shfl_xor(c0, off);
        MRG3(xa, xb, xc, a0, b0, c0);
    }
    if (lane == 0) { tr[i] = c0; rowcnt[i] = 0; }
}

#define CAND(v, i) do { \
    if ((v) >= tr[i] && (v) > 0.01f) { \
        int _s = atomicAdd(&rowcnt[i], 1); \
        if (_s < 8) { rowj[(size_t)(i) * 8 + _s] = j; roww[(size_t)(i) * 8 + _s] = (v); } \
    } } while (0)

__global__ __launch_bounds__(256) void k_col_pass(const float* __restrict__ P,
        const float* __restrict__ tr, float* __restrict__ part, int segrows,
        int* __restrict__ rowcnt, int* __restrict__ rowj, float* __restrict__ roww)
{
    int j = blockIdx.x * 256 + threadIdx.x;
    int i0 = blockIdx.y * segrows;
    float a0 = -1e30f, b0 = -1e30f, c0 = -1e30f;
    float a1 = -1e30f, b1 = -1e30f, c1 = -1e30f;
    float a2 = -1e30f, b2 = -1e30f, c2 = -1e30f;
    float a3 = -1e30f, b3 = -1e30f, c3 = -1e30f;
    float a4 = -1e30f, b4 = -1e30f, c4 = -1e30f;
    float a5 = -1e30f, b5 = -1e30f, c5 = -1e30f;
    float a6 = -1e30f, b6 = -1e30f, c6 = -1e30f;
    float a7 = -1e30f, b7 = -1e30f, c7 = -1e30f;
    for (int r = 0; r < segrows; r += 8) {
        int i = i0 + r;
        const float* col = P + (size_t)i * LDP + j;
        float v0 = col[0 * LDP];
        float v1 = col[1 * LDP];
        float v2 = col[2 * LDP];
        float v3 = col[3 * LDP];
        float v4 = col[4 * LDP];
        float v5 = col[5 * LDP];
        float v6 = col[6 * LDP];
        float v7 = col[7 * LDP];
        INS3(v0, a0, b0, c0);
        INS3(v1, a1, b1, c1);
        INS3(v2, a2, b2, c2);
        INS3(v3, a3, b3, c3);
        INS3(v4, a4, b4, c4);
        INS3(v5, a5, b5, c5);
        INS3(v6, a6, b6, c6);
        INS3(v7, a7, b7, c7);
        CAND(v0, i + 0);
        CAND(v1, i + 1);
        CAND(v2, i + 2);
        CAND(v3, i + 3);
        CAND(v4, i + 4);
        CAND(v5, i + 5);
        CAND(v6, i + 6);
        CAND(v7, i + 7);
    }
    MRG3(a1, b1, c1, a0, b0, c0);
    MRG3(a2, b2, c2, a0, b0, c0);
    MRG3(a3, b3, c3, a0, b0, c0);
    MRG3(a4, b4, c4, a0, b0, c0);
    MRG3(a5, b5, c5, a0, b0, c0);
    MRG3(a6, b6, c6, a0, b0, c0);
    MRG3(a7, b7, c7, a0, b0, c0);
    size_t o = ((size_t)blockIdx.y * NPV + j) * 3;
    part[o] = a0; part[o + 1] = b0; part[o + 2] = c0;
}

__global__ __launch_bounds__(64) void k_col_merge(const float* __restrict__ part,
        float* __restrict__ tc, int nseg)
{
    int j = blockIdx.x * 64 + threadIdx.x;
    float a = -1e30f, b = -1e30f, c = -1e30f;
    for (int s = 0; s < nseg; ++s) {
        size_t o = ((size_t)s * NPV + j) * 3;
        float x = part[o], y = part[o + 1], z = part[o + 2];
        MRG3(x, y, z, a, b, c);
    }
    tc[j] = c;
}

// Accumulate per-candidate contribution to the 52 moments (mean-shifted coords).
__device__ __forceinline__ void acc_pair(float* m, float w, float xs1, float ys1,
                                         float xs2, float ys2)
{
    m[0] += w;
    m[1] += w * xs1; m[2] += w * ys1; m[3] += w * (xs1 * xs1 + ys1 * ys1);
    m[4] += w * xs2; m[5] += w * ys2; m[6] += w * (xs2 * xs2 + ys2 * ys2);
    float a[9] = { xs1 * xs2, xs1 * ys2, xs1, ys1 * xs2, ys1 * ys2, ys1, xs2, ys2, 1.f };
    int idx = 7;
    #pragma unroll
    for (int u = 0; u < 9; ++u) {
        float wa = w * a[u];
        #pragma unroll
        for (int v = u; v < 9; ++v) { m[idx] = fmaf(wa, a[v], m[idx]); ++idx; }
    }
}

// One thread per row: filter candidates by tc, accumulate raw moments,
// wave-reduce, lane0 global atomicAdd. 48 blocks x 64 threads.
__global__ __launch_bounds__(64) void k_moments(const float* __restrict__ Kmat,
        const float* __restrict__ tc, const int* __restrict__ rowcnt,
        const int* __restrict__ rowj, const float* __restrict__ roww,
        float* __restrict__ mom)
{
    int i = blockIdx.x * 64 + threadIdx.x;
    float ki0, ki1, ki2, ki3, ki4, ki5;
    kinv6(Kmat, ki0, ki1, ki2, ki3, ki4, ki5);
    float m[NMOM];
    #pragma unroll
    for (int k = 0; k < NMOM; ++k) m[k] = 0.f;
    int n = rowcnt[i]; n = n > 8 ? 8 : n;
    const int4*   jp = (const int4*)(rowj + (size_t)i * 8);
    const float4* vp = (const float4*)(roww + (size_t)i * 8);
    int4  ja = jp[0], jb = jp[1];
    float4 va = vp[0], vb = vp[1];
    float xg = (float)(i & 63) - 31.5f, yg = (float)(i >> 6) - 23.5f;
    float xs1 = ki0 * xg + ki1 * yg;
    float ys1 = ki3 * xg + ki4 * yg;
#define ACC(S, JR, VR) do { \
    if ((S) < n) { int _j = (JR); float _w = (VR); \
        if (_w >= tc[_j]) { \
            float _xg = (float)(_j & 63) - 31.5f, _yg = (float)(_j >> 6) - 23.5f; \
            float xs2 = ki0 * _xg + ki1 * _yg; \
            float ys2 = ki3 * _xg + ki4 * _yg; \
            acc_pair(m, _w, xs1, ys1, xs2, ys2); \
        } } } while (0)
    ACC(0, ja.x, va.x); ACC(1, ja.y, va.y); ACC(2, ja.z, va.z); ACC(3, ja.w, va.w);
    ACC(4, jb.x, vb.x); ACC(5, jb.y, vb.y); ACC(6, jb.z, vb.z); ACC(7, jb.w, vb.w);
#undef ACC
    #pragma unroll
    for (int k = 0; k < NMOM; ++k) {
        #pragma unroll
        for (int off = 32; off; off >>= 1) m[k] += __shfl_xor(m[k], off);
    }
    if (threadIdx.x == 0) {
        #pragma unroll
        for (int k = 0; k < NMOM; ++k) atomicAdd(&mom[k], m[k]);
    }
}

__device__ __forceinline__ void mm3r(const float* A, const float* B, float* C) {
    #pragma unroll
    for (int r = 0; r < 3; ++r)
        #pragma unroll
        for (int c = 0; c < 3; ++c)
            C[r * 3 + c] = A[r * 3 + 0] * B[0 + c] + A[r * 3 + 1] * B[3 + c] + A[r * 3 + 2] * B[6 + c];
}

__device__ __forceinline__ float det3(const float* M) {
    return M[0] * (M[4] * M[8] - M[5] * M[7])
         - M[1] * (M[3] * M[8] - M[5] * M[6])
         + M[2] * (M[3] * M[7] - M[4] * M[6]);
}

// Single small block: congruence transform + matrix-power tails.
__global__ __launch_bounds__(128) void k_tail(const float* __restrict__ Kmat,
        const float* __restrict__ mom, float* __restrict__ out)
{
    __shared__ float sM[81], sY[81], sP[81], sT[81];
    __shared__ float sT1[9], sT2[9];
    int t = threadIdx.x;

    float ki0, ki1, ki2, ki3, ki4, ki5;
    kinv6(Kmat, ki0, ki1, ki2, ki3, ki4, ki5);
    float u0x = ki0 * 31.5f + ki1 * 23.5f + ki2;
    float u0y = ki3 * 31.5f + ki4 * 23.5f + ki5;

    float Sw = mom[0];
    float ws = Sw + EPSF;
    float c1x = mom[1] / ws, c1y = mom[2] / ws;
    float c2x = mom[4] / ws, c2y = mom[5] / ws;
    float q1 = (mom[3] - 2.f * (c1x * mom[1] + c1y * mom[2]) + (c1x * c1x + c1y * c1y) * Sw) / ws;
    float q2 = (mom[6] - 2.f * (c2x * mom[4] + c2y * mom[5]) + (c2x * c2x + c2y * c2y) * Sw) / ws;
    float md1 = sqrtf(fmaxf(q1, 0.f) + EPSF);
    float md2 = sqrtf(fmaxf(q2, 0.f) + EPSF);
    float s1 = 1.4142135623730951f / (md1 + EPSF);
    float s2 = 1.4142135623730951f / (md2 + EPSF);

    // M_raw (full 9x9 from 45) + shifted-frame T matrices into LDS.
    if (t < 81) {
        int r = t / 9, c = t % 9;
        int u = r < c ? r : c, v = r < c ? c : r;
        int idx = 7 + u * 9 - (u * (u + 1)) / 2 + v;
        sM[t] = mom[idx];
    }
    if (t == 0) {
        sT1[0] = s1; sT1[1] = 0.f; sT1[2] = -s1 * c1x;
        sT1[3] = 0.f; sT1[4] = s1; sT1[5] = -s1 * c1y;
        sT1[6] = 0.f; sT1[7] = 0.f; sT1[8] = 1.f;
        sT2[0] = s2; sT2[1] = 0.f; sT2[2] = -s2 * c2x;
        sT2[3] = 0.f; sT2[4] = s2; sT2[5] = -s2 * c2y;
        sT2[6] = 0.f; sT2[7] = 0.f; sT2[8] = 1.f;
    }
    __syncthreads();

    // Y = M_raw * L^T   (L[c][l] = T1[c/3][l/3]*T2[c%3][l%3])
    if (t < 81) {
        int k = t / 9, c = t % 9;
        float s = 0.f;
        #pragma unroll
        for (int l = 0; l < 9; ++l)
            s = fmaf(sM[k * 9 + l], sT1[(c / 3) * 3 + (l / 3)] * sT2[(c % 3) * 3 + (l % 3)], s);
        sY[t] = s;
    }
    __syncthreads();
    // M' = L * Y
    if (t < 81) {
        int r = t / 9, c = t % 9;
        float s = 0.f;
        #pragma unroll
        for (int k = 0; k < 9; ++k)
            s = fmaf(sT1[(r / 3) * 3 + (k / 3)] * sT2[(r % 3) * 3 + (k % 3)], sY[k * 9 + c], s);
        sP[t] = s;
    }
    __syncthreads();
    // Ms_hat = (lam*I - M')/lam  into sM (spectral norm <= 1, dominant eig >= 8/9)
    if (t < 81) {
        int r = t / 9, c = t % 9;
        float lam = sP[0] + sP[10] + sP[20] + sP[30] + sP[40] + sP[50] + sP[60] + sP[70] + sP[80];
        float il = 1.f / (lam + 1e-30f);
        sM[t] = ((r == c ? lam : 0.f) - sP[t]) * il;
    }
    __syncthreads();

#define MM81(DST, A, B) \
    if (t < 81) { \
        int _r = t / 9, _c = t % 9; \
        float _s = 0.f; \
        _Pragma("unroll") \
        for (int _k = 0; _k < 9; ++_k) _s = fmaf(A[_r * 9 + _k], B[_k * 9 + _c], _s); \
        DST[t] = _s; \
    } \
    __syncthreads();

    MM81(sY, sM, sM)   // P2   (kept)
    MM81(sP, sY, sY)   // P4
    MM81(sT, sP, sP)   // P8
    MM81(sP, sT, sT)   // P16  (kept)
    MM81(sT, sP, sP)   // P32
    MM81(sM, sT, sP)   // R  = P32*P16
    MM81(sT, sM, sY)   // P50 = R*P2

    if (t < 64) {
        // v = normalize(P50 * (1/3,...,1/3))
        float v9[9];
        float nrm = 0.f;
        #pragma unroll
        for (int r = 0; r < 9; ++r) {
            float s = 0.f;
            #pragma unroll
            for (int c = 0; c < 9; ++c) s += sT[r * 9 + c];
            v9[r] = s * (1.f / 3.f);
            nrm += v9[r] * v9[r];
        }
        nrm = sqrtf(nrm) + EPSF;
        #pragma unroll
        for (int r = 0; r < 9; ++r) v9[r] /= nrm;

        // E = T2_full^T * E_raw * T1_full   (full-frame centroids)
        float C1x = c1x + u0x, C1y = c1y + u0y;
        float C2x = c2x + u0x, C2y = c2y + u0y;
        float T1f[9] = { s1, 0.f, -s1 * C1x, 0.f, s1, -s1 * C1y, 0.f, 0.f, 1.f };
        float T2t[9] = { s2, 0.f, 0.f, 0.f, s2, 0.f, -s2 * C2x, -s2 * C2y, 1.f };
        float M1[9], Ee[9];
        mm3r(v9, T1f, M1);
        mm3r(T2t, M1, Ee);

        float B[9];
        #pragma unroll
        for (int r = 0; r < 3; ++r)
            #pragma unroll
            for (int c = 0; c < 3; ++c)
                B[r * 3 + c] = Ee[r] * Ee[c] + Ee[3 + r] * Ee[3 + c] + Ee[6 + r] * Ee[6 + c];
        float lam3 = B[0] + B[4] + B[8];
        float il3 = 1.f / (lam3 + 1e-30f);

        // lane parity 0 -> B/lam3 (v1 chain);  parity 1 -> (lam3*I - B)/lam3 (v3 chain)
        int parity = t & 1;
        float P1[9];
        #pragma unroll
        for (int k = 0; k < 9; ++k) {
            float d = (k == 0 || k == 4 || k == 8) ? lam3 : 0.f;
            P1[k] = (parity ? (d - B[k]) : B[k]) * il3;
        }
        float P2[9], P4[9], P8[9], P16[9], P32[9], R1[9], P50[9];
        mm3r(P1, P1, P2);
        mm3r(P2, P2, P4);
        mm3r(P4, P4, P8);
        mm3r(P8, P8, P16);
        mm3r(P16, P16, P32);
        mm3r(P32, P16, R1);
        mm3r(R1, P2, P50);
        float vx = (P50[0] + P50[1] + P50[2]) * 0.57735026918962584f;
        float vy = (P50[3] + P50[4] + P50[5]) * 0.57735026918962584f;
        float vz = (P50[6] + P50[7] + P50[8]) * 0.57735026918962584f;
        float vn = sqrtf(vx * vx + vy * vy + vz * vz) + EPSF;
        vx /= vn; vy /= vn; vz /= vn;

        float v3x = __shfl(vx, 1), v3y = __shfl(vy, 1), v3z = __shfl(vz, 1);

        if (t == 0) {
            float v1[3] = { vx, vy, vz };
            float v3[3] = { v3x, v3y, v3z };
            float v2[3];
            v2[0] = v3[1] * v1[2] - v3[2] * v1[1];
            v2[1] = v3[2] * v1[0] - v3[0] * v1[2];
            v2[2] = v3[0] * v1[1] - v3[1] * v1[0];
            float n2 = sqrtf(v2[0] * v2[0] + v2[1] * v2[1] + v2[2] * v2[2]) + EPSF;
            v2[0] /= n2; v2[1] /= n2; v2[2] /= n2;
            float V[9];
            #pragma unroll
            for (int r = 0; r < 3; ++r) { V[r * 3 + 0] = v1[r]; V[r * 3 + 1] = v2[r]; V[r * 3 + 2] = v3[r]; }
            float dV = det3(V);
            float sV = (dV > 0.f) ? 1.f : ((dV < 0.f) ? -1.f : 0.f);
            V[2] *= sV; V[5] *= sV; V[8] *= sV;
            float Ev1[3], Ev2[3];
            #pragma unroll
            for (int r = 0; r < 3; ++r) {
                Ev1[r] = Ee[r * 3] * V[0] + Ee[r * 3 + 1] * V[3] + Ee[r * 3 + 2] * V[6];
                Ev2[r] = Ee[r * 3] * V[1] + Ee[r * 3 + 1] * V[4] + Ee[r * 3 + 2] * V[7];
            }
            float s1n = sqrtf(Ev1[0] * Ev1[0] + Ev1[1] * Ev1[1] + Ev1[2] * Ev1[2]);
            float s2n = sqrtf(Ev2[0] * Ev2[0] + Ev2[1] * Ev2[1] + Ev2[2] * Ev2[2]);
            float s_avg = (s1n + s2n) * 0.5f;
            float u1[3], u2[3];
            #pragma unroll
            for (int r = 0; r < 3; ++r) { u1[r] = Ev1[r] / (s1n + EPSF); u2[r] = Ev2[r] / (s2n + EPSF); }
            #pragma unroll
            for (int r = 0; r < 3; ++r)
                #pragma unroll
                for (int c = 0; c < 3; ++c)
                    out[r * 3 + c] = s_avg * (u1[r] * V[c * 3 + 0] + u2[r] * V[c * 3 + 1]);
        }
    }
}

extern "C" void kernel_launch(void* const* d_in, const int* in_sizes, int n_in,
                              void* d_out, int out_size, void* d_ws, size_t ws_size,
                              hipStream_t stream)
{
    const float* P = (const float*)d_in[0];
    const float* K = (const float*)d_in[1];
    float* out = (float*)d_out;

    float* fws    = (float*)d_ws;
    float* tr     = fws;                      // N
    float* tc     = tr + NPV;                 // N
    float* roww   = tc + NPV;                 // 8N
    int*   rowj   = (int*)(roww + 8 * NPV);   // 8N
    int*   rowcnt = rowj + 8 * NPV;           // N
    float* mom    = (float*)(rowcnt + NPV);   // 52 (+pad to 64)
    float* part   = mom + 64;                 // 3N * nseg

    size_t fixed_bytes = ((size_t)NPV * 19 + 64) * sizeof(float);
    int nseg = 16;
    for (int cand = 128; cand >= 16; cand >>= 1) {
        if (ws_size >= fixed_bytes + (size_t)cand * NPV * 3 * sizeof(float)) { nseg = cand; break; }
    }
    int segrows = NPV / nseg;

    k_row_top3<<<NPV / 4, 256, 0, stream>>>(P, tr, rowcnt, mom);
    dim3 g2(NPV / 256, nseg);
    k_col_pass<<<g2, 256, 0, stream>>>(P, tr, part, segrows, rowcnt, rowj, roww);
    k_col_merge<<<NPV / 64, 64, 0, stream>>>(part, tc, nseg);
    k_moments<<<NPV / 64, 64, 0, stream>>>(K, tc, rowcnt, rowj, roww, mom);
    k_tail<<<1, 128, 0, stream>>>(K, mom, out);
}

// Round 7
// 38.338 us; speedup vs baseline: 5.9275x; 2.4423x over previous
//
#include <hip/hip_runtime.h>
#include <math.h>

#define NPV 3072
#define LDP 3073
#define EPSF 1e-8f
#define NMOM 52   // [0..6] w-moments (Sw, Sx1,Sy1,Sq1, Sx2,Sy2,Sq2), [7..51] 45 sym tensor
#define NROWBLK (NPV / 64)   // 48 moment blocks

// Branchless insert of v into sorted-descending triple (a >= b >= c).
#define INS3(v, a, b, c) do { \
    float _m1 = fminf((a), (v)); (a) = fmaxf((a), (v)); \
    float _m2 = fminf((b), _m1); (b) = fmaxf((b), _m1); \
    (c) = fmaxf((c), _m2); } while (0)

#define MRG3(x, y, z, a, b, c) do { \
    INS3((x), a, b, c); INS3((y), a, b, c); INS3((z), a, b, c); } while (0)

__device__ __forceinline__ void kinv6(const float* __restrict__ Kmat,
        float& ki0, float& ki1, float& ki2, float& ki3, float& ki4, float& ki5)
{
    float k00 = Kmat[0], k01 = Kmat[1], k02 = Kmat[2];
    float k10 = Kmat[3], k11 = Kmat[4], k12 = Kmat[5];
    float k20 = Kmat[6], k21 = Kmat[7], k22 = Kmat[8];
    float det = k00 * (k11 * k22 - k12 * k21) - k01 * (k10 * k22 - k12 * k20) + k02 * (k10 * k21 - k11 * k20);
    float id = 1.0f / det;
    ki0 = (k11 * k22 - k12 * k21) * id; ki1 = (k02 * k21 - k01 * k22) * id; ki2 = (k01 * k12 - k02 * k11) * id;
    ki3 = (k12 * k20 - k10 * k22) * id; ki4 = (k00 * k22 - k02 * k20) * id; ki5 = (k02 * k10 - k00 * k12) * id;
}

// One wave per row (4 rows/block), branchless values-only top-3.
__global__ __launch_bounds__(256) void k_row_top3(const float* __restrict__ P,
        float* __restrict__ tr, int* __restrict__ rowcnt)
{
    int lane = threadIdx.x & 63;
    int i = blockIdx.x * 4 + (threadIdx.x >> 6);
    const float* row = P + (size_t)i * LDP;
    float a0 = -1e30f, b0 = -1e30f, c0 = -1e30f;
    float a1 = -1e30f, b1 = -1e30f, c1 = -1e30f;
    float a2 = -1e30f, b2 = -1e30f, c2 = -1e30f;
    float a3 = -1e30f, b3 = -1e30f, c3 = -1e30f;
    #pragma unroll
    for (int r = 0; r < 48; r += 4) {
        float v0 = row[(r + 0) * 64 + lane];
        float v1 = row[(r + 1) * 64 + lane];
        float v2 = row[(r + 2) * 64 + lane];
        float v3 = row[(r + 3) * 64 + lane];
        INS3(v0, a0, b0, c0);
        INS3(v1, a1, b1, c1);
        INS3(v2, a2, b2, c2);
        INS3(v3, a3, b3, c3);
    }
    MRG3(a1, b1, c1, a0, b0, c0);
    MRG3(a2, b2, c2, a0, b0, c0);
    MRG3(a3, b3, c3, a0, b0, c0);
    #pragma unroll
    for (int off = 1; off < 64; off <<= 1) {
        float xa = __shfl_xor(a0, off);
        float xb = __shfl_xor(b0, off);
        float xc = __shfl_xor(c0, off);
        MRG3(xa, xb, xc, a0, b0, c0);
    }
    if (lane == 0) { tr[i] = c0; rowcnt[i] = 0; }
}

#define CAND(v, i) do { \
    if ((v) >= tr[i] && (v) > 0.01f) { \
        int _s = atomicAdd(&rowcnt[i], 1); \
        if (_s < 8) { rowj[(size_t)(i) * 8 + _s] = j; roww[(size_t)(i) * 8 + _s] = (v); } \
    } } while (0)

__global__ __launch_bounds__(256) void k_col_pass(const float* __restrict__ P,
        const float* __restrict__ tr, float4* __restrict__ part, int segrows,
        int* __restrict__ rowcnt, int* __restrict__ rowj, float* __restrict__ roww)
{
    int j = blockIdx.x * 256 + threadIdx.x;
    int i0 = blockIdx.y * segrows;
    float a0 = -1e30f, b0 = -1e30f, c0 = -1e30f;
    float a1 = -1e30f, b1 = -1e30f, c1 = -1e30f;
    float a2 = -1e30f, b2 = -1e30f, c2 = -1e30f;
    float a3 = -1e30f, b3 = -1e30f, c3 = -1e30f;
    float a4 = -1e30f, b4 = -1e30f, c4 = -1e30f;
    float a5 = -1e30f, b5 = -1e30f, c5 = -1e30f;
    float a6 = -1e30f, b6 = -1e30f, c6 = -1e30f;
    float a7 = -1e30f, b7 = -1e30f, c7 = -1e30f;
    for (int r = 0; r < segrows; r += 8) {
        int i = i0 + r;
        const float* col = P + (size_t)i * LDP + j;
        float v0 = col[0 * LDP];
        float v1 = col[1 * LDP];
        float v2 = col[2 * LDP];
        float v3 = col[3 * LDP];
        float v4 = col[4 * LDP];
        float v5 = col[5 * LDP];
        float v6 = col[6 * LDP];
        float v7 = col[7 * LDP];
        INS3(v0, a0, b0, c0);
        INS3(v1, a1, b1, c1);
        INS3(v2, a2, b2, c2);
        INS3(v3, a3, b3, c3);
        INS3(v4, a4, b4, c4);
        INS3(v5, a5, b5, c5);
        INS3(v6, a6, b6, c6);
        INS3(v7, a7, b7, c7);
        CAND(v0, i + 0);
        CAND(v1, i + 1);
        CAND(v2, i + 2);
        CAND(v3, i + 3);
        CAND(v4, i + 4);
        CAND(v5, i + 5);
        CAND(v6, i + 6);
        CAND(v7, i + 7);
    }
    MRG3(a1, b1, c1, a0, b0, c0);
    MRG3(a2, b2, c2, a0, b0, c0);
    MRG3(a3, b3, c3, a0, b0, c0);
    MRG3(a4, b4, c4, a0, b0, c0);
    MRG3(a5, b5, c5, a0, b0, c0);
    MRG3(a6, b6, c6, a0, b0, c0);
    MRG3(a7, b7, c7, a0, b0, c0);
    part[(size_t)blockIdx.y * NPV + j] = make_float4(a0, b0, c0, 0.f);
}

// 16 threads per column, NSEG/16 segments each, 4-step shfl merge.
// grid NPV/16 blocks x 256 threads. NSEG compile-time -> no scratch.
template<int NSEG>
__global__ __launch_bounds__(256) void k_col_merge(const float4* __restrict__ part,
        float* __restrict__ tc)
{
    int sub = threadIdx.x & 15;
    int j = blockIdx.x * 16 + (threadIdx.x >> 4);
    constexpr int CNT = NSEG / 16;
    float4 buf[CNT];
    #pragma unroll
    for (int k = 0; k < CNT; ++k)
        buf[k] = part[(size_t)(sub + (k << 4)) * NPV + j];
    float a = -1e30f, b = -1e30f, c = -1e30f;
    #pragma unroll
    for (int k = 0; k < CNT; ++k) MRG3(buf[k].x, buf[k].y, buf[k].z, a, b, c);
    #pragma unroll
    for (int off = 1; off < 16; off <<= 1) {
        float xa = __shfl_xor(a, off);
        float xb = __shfl_xor(b, off);
        float xc = __shfl_xor(c, off);
        MRG3(xa, xb, xc, a, b, c);
    }
    if (sub == 0) tc[j] = c;
}

// Accumulate per-candidate contribution to the 52 moments (mean-shifted coords).
__device__ __forceinline__ void acc_pair(float* m, float w, float xs1, float ys1,
                                         float xs2, float ys2)
{
    m[0] += w;
    m[1] += w * xs1; m[2] += w * ys1; m[3] += w * (xs1 * xs1 + ys1 * ys1);
    m[4] += w * xs2; m[5] += w * ys2; m[6] += w * (xs2 * xs2 + ys2 * ys2);
    float a[9] = { xs1 * xs2, xs1 * ys2, xs1, ys1 * xs2, ys1 * ys2, ys1, xs2, ys2, 1.f };
    int idx = 7;
    #pragma unroll
    for (int u = 0; u < 9; ++u) {
        float wa = w * a[u];
        #pragma unroll
        for (int v = u; v < 9; ++v) { m[idx] = fmaf(wa, a[v], m[idx]); ++idx; }
    }
}

// One thread per row; wave-reduce; per-block partial written plain (no atomics).
__global__ __launch_bounds__(64) void k_moments(const float* __restrict__ Kmat,
        const float* __restrict__ tc, const int* __restrict__ rowcnt,
        const int* __restrict__ rowj, const float* __restrict__ roww,
        float* __restrict__ momp)
{
    int i = blockIdx.x * 64 + threadIdx.x;
    float ki0, ki1, ki2, ki3, ki4, ki5;
    kinv6(Kmat, ki0, ki1, ki2, ki3, ki4, ki5);
    float m[NMOM];
    #pragma unroll
    for (int k = 0; k < NMOM; ++k) m[k] = 0.f;
    int n = rowcnt[i]; n = n > 8 ? 8 : n;
    const int4*   jp = (const int4*)(rowj + (size_t)i * 8);
    const float4* vp = (const float4*)(roww + (size_t)i * 8);
    int4  ja = jp[0], jb = jp[1];
    float4 va = vp[0], vb = vp[1];
    float xg = (float)(i & 63) - 31.5f, yg = (float)(i >> 6) - 23.5f;
    float xs1 = ki0 * xg + ki1 * yg;
    float ys1 = ki3 * xg + ki4 * yg;
#define ACC(S, JR, VR) do { \
    if ((S) < n) { int _j = (JR); float _w = (VR); \
        if (_w >= tc[_j]) { \
            float _xg = (float)(_j & 63) - 31.5f, _yg = (float)(_j >> 6) - 23.5f; \
            float xs2 = ki0 * _xg + ki1 * _yg; \
            float ys2 = ki3 * _xg + ki4 * _yg; \
            acc_pair(m, _w, xs1, ys1, xs2, ys2); \
        } } } while (0)
    ACC(0, ja.x, va.x); ACC(1, ja.y, va.y); ACC(2, ja.z, va.z); ACC(3, ja.w, va.w);
    ACC(4, jb.x, vb.x); ACC(5, jb.y, vb.y); ACC(6, jb.z, vb.z); ACC(7, jb.w, vb.w);
#undef ACC
    #pragma unroll
    for (int k = 0; k < NMOM; ++k) {
        #pragma unroll
        for (int off = 32; off; off >>= 1) m[k] += __shfl_xor(m[k], off);
    }
    if (threadIdx.x == 0) {
        float* dst = momp + (size_t)blockIdx.x * 64;
        #pragma unroll
        for (int k = 0; k < NMOM; ++k) dst[k] = m[k];
    }
}

__device__ __forceinline__ void mm3r(const float* A, const float* B, float* C) {
    #pragma unroll
    for (int r = 0; r < 3; ++r)
        #pragma unroll
        for (int c = 0; c < 3; ++c)
            C[r * 3 + c] = A[r * 3 + 0] * B[0 + c] + A[r * 3 + 1] * B[3 + c] + A[r * 3 + 2] * B[6 + c];
}

__device__ __forceinline__ float det3(const float* M) {
    return M[0] * (M[4] * M[8] - M[5] * M[7])
         - M[1] * (M[3] * M[8] - M[5] * M[6])
         + M[2] * (M[3] * M[7] - M[4] * M[6]);
}

// Single small block: partial-reduce + congruence transform + matrix-power tails.
__global__ __launch_bounds__(128) void k_tail(const float* __restrict__ Kmat,
        const float* __restrict__ momp, float* __restrict__ out)
{
    __shared__ float sMom[NMOM];
    __shared__ float sM[81], sY[81], sP[81], sT[81];
    __shared__ float sT1[9], sT2[9];
    int t = threadIdx.x;

    if (t < NMOM) {
        float s = 0.f;
        for (int b = 0; b < NROWBLK; ++b) s += momp[(size_t)b * 64 + t];
        sMom[t] = s;
    }
    __syncthreads();

    float ki0, ki1, ki2, ki3, ki4, ki5;
    kinv6(Kmat, ki0, ki1, ki2, ki3, ki4, ki5);
    float u0x = ki0 * 31.5f + ki1 * 23.5f + ki2;
    float u0y = ki3 * 31.5f + ki4 * 23.5f + ki5;

    float Sw = sMom[0];
    float ws = Sw + EPSF;
    float c1x = sMom[1] / ws, c1y = sMom[2] / ws;
    float c2x = sMom[4] / ws, c2y = sMom[5] / ws;
    float q1 = (sMom[3] - 2.f * (c1x * sMom[1] + c1y * sMom[2]) + (c1x * c1x + c1y * c1y) * Sw) / ws;
    float q2 = (sMom[6] - 2.f * (c2x * sMom[4] + c2y * sMom[5]) + (c2x * c2x + c2y * c2y) * Sw) / ws;
    float md1 = sqrtf(fmaxf(q1, 0.f) + EPSF);
    float md2 = sqrtf(fmaxf(q2, 0.f) + EPSF);
    float s1 = 1.4142135623730951f / (md1 + EPSF);
    float s2 = 1.4142135623730951f / (md2 + EPSF);

    // M_raw (full 9x9 from 45) + shifted-frame T matrices into LDS.
    if (t < 81) {
        int r = t / 9, c = t % 9;
        int u = r < c ? r : c, v = r < c ? c : r;
        int idx = 7 + u * 9 - (u * (u + 1)) / 2 + v;
        sM[t] = sMom[idx];
    }
    if (t == 0) {
        sT1[0] = s1; sT1[1] = 0.f; sT1[2] = -s1 * c1x;
        sT1[3] = 0.f; sT1[4] = s1; sT1[5] = -s1 * c1y;
        sT1[6] = 0.f; sT1[7] = 0.f; sT1[8] = 1.f;
        sT2[0] = s2; sT2[1] = 0.f; sT2[2] = -s2 * c2x;
        sT2[3] = 0.f; sT2[4] = s2; sT2[5] = -s2 * c2y;
        sT2[6] = 0.f; sT2[7] = 0.f; sT2[8] = 1.f;
    }
    __syncthreads();

    // Y = M_raw * L^T   (L[c][l] = T1[c/3][l/3]*T2[c%3][l%3])
    if (t < 81) {
        int k = t / 9, c = t % 9;
        float s = 0.f;
        #pragma unroll
        for (int l = 0; l < 9; ++l)
            s = fmaf(sM[k * 9 + l], sT1[(c / 3) * 3 + (l / 3)] * sT2[(c % 3) * 3 + (l % 3)], s);
        sY[t] = s;
    }
    __syncthreads();
    // M' = L * Y
    if (t < 81) {
        int r = t / 9, c = t % 9;
        float s = 0.f;
        #pragma unroll
        for (int k = 0; k < 9; ++k)
            s = fmaf(sT1[(r / 3) * 3 + (k / 3)] * sT2[(r % 3) * 3 + (k % 3)], sY[k * 9 + c], s);
        sP[t] = s;
    }
    __syncthreads();
    // Ms_hat = (lam*I - M')/lam  into sM (spectral norm <= 1, dominant eig >= 8/9)
    if (t < 81) {
        int r = t / 9, c = t % 9;
        float lam = sP[0] + sP[10] + sP[20] + sP[30] + sP[40] + sP[50] + sP[60] + sP[70] + sP[80];
        float il = 1.f / (lam + 1e-30f);
        sM[t] = ((r == c ? lam : 0.f) - sP[t]) * il;
    }
    __syncthreads();

#define MM81(DST, A, B) \
    if (t < 81) { \
        int _r = t / 9, _c = t % 9; \
        float _s = 0.f; \
        _Pragma("unroll") \
        for (int _k = 0; _k < 9; ++_k) _s = fmaf(A[_r * 9 + _k], B[_k * 9 + _c], _s); \
        DST[t] = _s; \
    } \
    __syncthreads();

    MM81(sY, sM, sM)   // P2   (kept)
    MM81(sP, sY, sY)   // P4
    MM81(sT, sP, sP)   // P8
    MM81(sP, sT, sT)   // P16  (kept)
    MM81(sT, sP, sP)   // P32
    MM81(sM, sT, sP)   // R  = P32*P16
    MM81(sT, sM, sY)   // P50 = R*P2

    if (t < 64) {
        // v = normalize(P50 * (1/3,...,1/3))
        float v9[9];
        float nrm = 0.f;
        #pragma unroll
        for (int r = 0; r < 9; ++r) {
            float s = 0.f;
            #pragma unroll
            for (int c = 0; c < 9; ++c) s += sT[r * 9 + c];
            v9[r] = s * (1.f / 3.f);
            nrm += v9[r] * v9[r];
        }
        nrm = sqrtf(nrm) + EPSF;
        #pragma unroll
        for (int r = 0; r < 9; ++r) v9[r] /= nrm;

        // E = T2_full^T * E_raw * T1_full   (full-frame centroids)
        float C1x = c1x + u0x, C1y = c1y + u0y;
        float C2x = c2x + u0x, C2y = c2y + u0y;
        float T1f[9] = { s1, 0.f, -s1 * C1x, 0.f, s1, -s1 * C1y, 0.f, 0.f, 1.f };
        float T2t[9] = { s2, 0.f, 0.f, 0.f, s2, 0.f, -s2 * C2x, -s2 * C2y, 1.f };
        float M1[9], Ee[9];
        mm3r(v9, T1f, M1);
        mm3r(T2t, M1, Ee);

        float B[9];
        #pragma unroll
        for (int r = 0; r < 3; ++r)
            #pragma unroll
            for (int c = 0; c < 3; ++c)
                B[r * 3 + c] = Ee[r] * Ee[c] + Ee[3 + r] * Ee[3 + c] + Ee[6 + r] * Ee[6 + c];
        float lam3 = B[0] + B[4] + B[8];
        float il3 = 1.f / (lam3 + 1e-30f);

        // lane parity 0 -> B/lam3 (v1 chain);  parity 1 -> (lam3*I - B)/lam3 (v3 chain)
        int parity = t & 1;
        float P1[9];
        #pragma unroll
        for (int k = 0; k < 9; ++k) {
            float d = (k == 0 || k == 4 || k == 8) ? lam3 : 0.f;
            P1[k] = (parity ? (d - B[k]) : B[k]) * il3;
        }
        float P2[9], P4[9], P8[9], P16[9], P32[9], R1[9], P50[9];
        mm3r(P1, P1, P2);
        mm3r(P2, P2, P4);
        mm3r(P4, P4, P8);
        mm3r(P8, P8, P16);
        mm3r(P16, P16, P32);
        mm3r(P32, P16, R1);
        mm3r(R1, P2, P50);
        float vx = (P50[0] + P50[1] + P50[2]) * 0.57735026918962584f;
        float vy = (P50[3] + P50[4] + P50[5]) * 0.57735026918962584f;
        float vz = (P50[6] + P50[7] + P50[8]) * 0.57735026918962584f;
        float vn = sqrtf(vx * vx + vy * vy + vz * vz) + EPSF;
        vx /= vn; vy /= vn; vz /= vn;

        float v3x = __shfl(vx, 1), v3y = __shfl(vy, 1), v3z = __shfl(vz, 1);

        if (t == 0) {
            float v1[3] = { vx, vy, vz };
            float v3[3] = { v3x, v3y, v3z };
            float v2[3];
            v2[0] = v3[1] * v1[2] - v3[2] * v1[1];
            v2[1] = v3[2] * v1[0] - v3[0] * v1[2];
            v2[2] = v3[0] * v1[1] - v3[1] * v1[0];
            float n2 = sqrtf(v2[0] * v2[0] + v2[1] * v2[1] + v2[2] * v2[2]) + EPSF;
            v2[0] /= n2; v2[1] /= n2; v2[2] /= n2;
            float V[9];
            #pragma unroll
            for (int r = 0; r < 3; ++r) { V[r * 3 + 0] = v1[r]; V[r * 3 + 1] = v2[r]; V[r * 3 + 2] = v3[r]; }
            float dV = det3(V);
            float sV = (dV > 0.f) ? 1.f : ((dV < 0.f) ? -1.f : 0.f);
            V[2] *= sV; V[5] *= sV; V[8] *= sV;
            float Ev1[3], Ev2[3];
            #pragma unroll
            for (int r = 0; r < 3; ++r) {
                Ev1[r] = Ee[r * 3] * V[0] + Ee[r * 3 + 1] * V[3] + Ee[r * 3 + 2] * V[6];
                Ev2[r] = Ee[r * 3] * V[1] + Ee[r * 3 + 1] * V[4] + Ee[r * 3 + 2] * V[7];
            }
            float s1n = sqrtf(Ev1[0] * Ev1[0] + Ev1[1] * Ev1[1] + Ev1[2] * Ev1[2]);
            float s2n = sqrtf(Ev2[0] * Ev2[0] + Ev2[1] * Ev2[1] + Ev2[2] * Ev2[2]);
            float s_avg = (s1n + s2n) * 0.5f;
            float u1[3], u2[3];
            #pragma unroll
            for (int r = 0; r < 3; ++r) { u1[r] = Ev1[r] / (s1n + EPSF); u2[r] = Ev2[r] / (s2n + EPSF); }
            #pragma unroll
            for (int r = 0; r < 3; ++r)
                #pragma unroll
                for (int c = 0; c < 3; ++c)
                    out[r * 3 + c] = s_avg * (u1[r] * V[c * 3 + 0] + u2[r] * V[c * 3 + 1]);
        }
    }
}

extern "C" void kernel_launch(void* const* d_in, const int* in_sizes, int n_in,
                              void* d_out, int out_size, void* d_ws, size_t ws_size,
                              hipStream_t stream)
{
    const float* P = (const float*)d_in[0];
    const float* K = (const float*)d_in[1];
    float* out = (float*)d_out;

    float* fws    = (float*)d_ws;
    float* tr     = fws;                          // N
    float* tc     = tr + NPV;                     // N
    float* roww   = tc + NPV;                     // 8N
    int*   rowj   = (int*)(roww + 8 * NPV);       // 8N
    int*   rowcnt = rowj + 8 * NPV;               // N
    float* momp   = (float*)(rowcnt + NPV);       // 48*64
    float4* part  = (float4*)(momp + NROWBLK * 64); // N*nseg float4 (16B-aligned: 19N+3072 floats = 245760 B)

    size_t fixed_bytes = ((size_t)NPV * 19 + NROWBLK * 64) * sizeof(float);
    int nseg = 16;
    for (int cand = 128; cand >= 16; cand >>= 1) {
        if (ws_size >= fixed_bytes + (size_t)cand * NPV * sizeof(float4)) { nseg = cand; break; }
    }
    int segrows = NPV / nseg;

    k_row_top3<<<NPV / 4, 256, 0, stream>>>(P, tr, rowcnt);
    dim3 g2(NPV / 256, nseg);
    k_col_pass<<<g2, 256, 0, stream>>>(P, tr, part, segrows, rowcnt, rowj, roww);
    switch (nseg) {
        case 128: k_col_merge<128><<<NPV / 16, 256, 0, stream>>>(part, tc); break;
        case 64:  k_col_merge<64><<<NPV / 16, 256, 0, stream>>>(part, tc); break;
        case 32:  k_col_merge<32><<<NPV / 16, 256, 0, stream>>>(part, tc); break;
        default:  k_col_merge<16><<<NPV / 16, 256, 0, stream>>>(part, tc); break;
    }
    k_moments<<<NPV / 64, 64, 0, stream>>>(K, tc, rowcnt, rowj, roww, momp);
    k_tail<<<1, 128, 0, stream>>>(K, momp, out);
}